// Round 1
// baseline (114.606 us; speedup 1.0000x reference)
//
#include <hip/hip_runtime.h>

// RNN_classifier: L=128 sequential steps over D=262144 independent columns,
// then out[t] = sigmoid(dot(x_bar[t], fc_w) + fc_b), out_size = 128 (fp32).
//
// Memory-bound: 671 MB streamed once -> ~107 us floor @ 6.3 TB/s.

#define L     128
#define DCOLS 262144
#define TPB   256
#define NWAVE (TPB / 64)
#define NBLK  (DCOLS / (2 * TPB))   // 512 blocks, float2 per thread

__device__ __forceinline__ float wred(float v) {
#pragma unroll
    for (int o = 32; o > 0; o >>= 1) v += __shfl_xor(v, o, 64);
    return v;
}

__device__ __forceinline__ float rcpf(float x) { return __builtin_amdgcn_rcpf(x); }

__device__ __forceinline__ float ftanh(float a) {
    a = fminf(fmaxf(a, -15.f), 15.f);          // avoid exp overflow -> NaN
    float e = __expf(-2.f * a);                // v_exp_f32
    return (1.f - e) * rcpf(1.f + e);
}

__device__ __forceinline__ float fsig(float z) {
    return rcpf(1.f + __expf(-z));             // inf-safe: 1/(1+inf) = 0
}

__global__ __launch_bounds__(TPB) void rnn_main(
    const float* __restrict__ x,  const float* __restrict__ wx,
    const float* __restrict__ wg, const float* __restrict__ wu,
    const float* __restrict__ m,  const float* __restrict__ fcw,
    float* __restrict__ part)
{
    __shared__ float lacc[NWAVE][L];
    const int tid  = threadIdx.x;
    const int lane = tid & 63;
    const int wid  = tid >> 6;
    const int col2 = blockIdx.x * TPB + tid;   // float2 column index
    const int stride2 = DCOLS / 2;

    const float2* px  = (const float2*)x  + col2;
    const float2* pm  = (const float2*)m  + col2;
    const float2* pwx = (const float2*)wx + col2;
    const float2* pwu = (const float2*)wu + col2;
    const float2* pwg = (const float2*)wg + col2;

    const float2 fw = ((const float2*)fcw)[col2];

    // ---- t = 0 ----
    float2 x0  = px[0];
    float2 wx0 = pwx[0];
    float2 wg0 = pwg[0];

    float2 h0, h, xb;
    h0.x = ftanh(x0.x * wx0.x);  h0.y = ftanh(x0.y * wx0.y);
    xb.x = h0.x * wg0.x + x0.x;  xb.y = h0.y * wg0.y + x0.y;   // xbar1
    h = h0;

    {   // x_bar[0] = x[0]
        float s = wred(x0.x * fw.x + x0.y * fw.y);
        if (lane == 0) lacc[wid][0] = s;
    }

    // prefetch t = 1
    float2 xn  = px[stride2];
    float2 mn  = pm[stride2];
    float2 wxn = pwx[stride2];
    float2 wun = pwu[stride2];
    float2 wgn = pwg[stride2];

    for (int t = 1; t < L; ++t) {
        float2 xc = xn, mc = mn, wxc = wxn, wuc = wun, wgc = wgn;
        if (t < L - 1) {                       // prefetch t+1 while computing t
            const int o = (t + 1) * stride2;
            xn = px[o]; mn = pm[o]; wxn = pwx[o]; wun = pwu[o]; wgn = pwg[o];
        }

        // emit pre-update carry: x_bar[t]
        float s = wred(xb.x * fw.x + xb.y * fw.y);
        if (lane == 0) lacc[wid][t] = s;

        // carry update with row-t data
        {
            float xt = xc.x * mc.x + xb.x * (1.f - mc.x);
            float u  = ftanh(xt * wxc.x);
            float f  = fsig(h.x + u * wuc.x) * mc.x;
            float hn = f * h.x + (1.f - f) * u;
            h.x  = fmaxf(hn, h0.x);            // h0 + relu(h - h0)
            xb.x = h.x * wgc.x + xt;
        }
        {
            float xt = xc.y * mc.y + xb.y * (1.f - mc.y);
            float u  = ftanh(xt * wxc.y);
            float f  = fsig(h.y + u * wuc.y) * mc.y;
            float hn = f * h.y + (1.f - f) * u;
            h.y  = fmaxf(hn, h0.y);
            xb.y = h.y * wgc.y + xt;
        }
    }

    __syncthreads();
    if (tid < L) {
        float s = 0.f;
#pragma unroll
        for (int w = 0; w < NWAVE; ++w) s += lacc[w][tid];
        part[blockIdx.x * L + tid] = s;
    }
}

__global__ __launch_bounds__(64) void rnn_finish(
    const float* __restrict__ part, const float* __restrict__ fcb,
    float* __restrict__ out)
{
    const int t    = blockIdx.x;   // 0..127
    const int lane = threadIdx.x;  // 64
    float s = 0.f;
    for (int b = lane; b < NBLK; b += 64) s += part[b * L + t];
    s = wred(s);
    if (lane == 0) out[t] = fsig(s + fcb[0]);
}

extern "C" void kernel_launch(void* const* d_in, const int* in_sizes, int n_in,
                              void* d_out, int out_size, void* d_ws, size_t ws_size,
                              hipStream_t stream) {
    // setup_inputs order: x, weight_x, weight_g, weight_u, mask, fc_w, fc_b
    const float* x   = (const float*)d_in[0];
    const float* wx  = (const float*)d_in[1];
    const float* wg  = (const float*)d_in[2];
    const float* wu  = (const float*)d_in[3];
    const float* m   = (const float*)d_in[4];
    const float* fcw = (const float*)d_in[5];
    const float* fcb = (const float*)d_in[6];
    float* out  = (float*)d_out;
    float* part = (float*)d_ws;    // NBLK * L floats = 256 KB

    rnn_main<<<NBLK, TPB, 0, stream>>>(x, wx, wg, wu, m, fcw, part);
    rnn_finish<<<L, 64, 0, stream>>>(part, fcb, out);
}